// Round 6
// baseline (433.515 us; speedup 1.0000x reference)
//
#include <hip/hip_runtime.h>
#include <hip/hip_bf16.h>
#include <cmath>

#define NFEAT 1024
#define NHID  512
#define NLAYERS 8
#define NDIA 48
#define DIAL 64
#define NROW (NDIA*DIAL)   // 3072
#define NROW3 (3*NROW)     // 9216

typedef short bf16x8 __attribute__((ext_vector_type(8)));
typedef float f32x4  __attribute__((ext_vector_type(4)));
typedef unsigned short u16x8 __attribute__((ext_vector_type(8)));
typedef unsigned short u16x4 __attribute__((ext_vector_type(4)));
typedef unsigned short ushort_t;

__device__ __forceinline__ unsigned short f2bf(float x) {
  __hip_bfloat16 h = __float2bfloat16(x);
  return __builtin_bit_cast(unsigned short, h);
}
__device__ __forceinline__ float bf2f(unsigned short u) {
  __hip_bfloat16 h = __builtin_bit_cast(__hip_bfloat16, u);
  return __bfloat162float(h);
}

__device__ __forceinline__ void gload16(const void* g, void* l) {
  __builtin_amdgcn_global_load_lds(
      (const __attribute__((address_space(1))) void*)g,
      (__attribute__((address_space(3))) void*)l, 16, 0, 0);
}

// ---------- fused: row-norm + bf16 convert (raw and normalized) ----------
__global__ __launch_bounds__(256) void k_prep(const float* __restrict__ a, const float* __restrict__ v,
                      const float* __restrict__ l, ushort_t* __restrict__ Abuf,
                      ushort_t* __restrict__ Xn) {
  int gid = blockIdx.x * 256 + threadIdx.x;
  int row = gid >> 6, lane = gid & 63;
  int m = row / NROW, r = row % NROW;
  const float* src = (m == 0 ? a : (m == 1 ? v : l)) + (size_t)r * NFEAT;
  float4 x[4];
  float s = 0.f;
#pragma unroll
  for (int q = 0; q < 4; ++q) {
    x[q] = *reinterpret_cast<const float4*>(src + lane * 4 + q * 256);
    s += x[q].x*x[q].x + x[q].y*x[q].y + x[q].z*x[q].z + x[q].w*x[q].w;
  }
#pragma unroll
  for (int off = 32; off; off >>= 1) s += __shfl_xor(s, off);
  float inv = rsqrtf(s);
  ushort_t* da = Abuf + (size_t)row * NFEAT;
  ushort_t* dn = Xn + (size_t)row * NFEAT;
#pragma unroll
  for (int q = 0; q < 4; ++q) {
    u16x4 oa, on;
    oa[0] = f2bf(x[q].x); oa[1] = f2bf(x[q].y); oa[2] = f2bf(x[q].z); oa[3] = f2bf(x[q].w);
    on[0] = f2bf(x[q].x * inv); on[1] = f2bf(x[q].y * inv);
    on[2] = f2bf(x[q].z * inv); on[3] = f2bf(x[q].w * inv);
    *reinterpret_cast<u16x4*>(da + lane * 4 + q * 256) = oa;
    *reinterpret_cast<u16x4*>(dn + lane * 4 + q * 256) = on;
  }
}

// ---------- MFMA Gram -> acos -> fused degree+normalize -> bf16 S + dinv ----------
__global__ __launch_bounds__(256) void k_simm(const ushort_t* __restrict__ Xn,
                      ushort_t* __restrict__ Sbf, float* __restrict__ dinv) {
  __shared__ short Xs[2][4096];
  __shared__ float simS[64][73];
  int blk = blockIdx.x;
  const ushort_t* Xb = Xn + (size_t)blk * 64 * NFEAT;
  int t = threadIdx.x, w = t >> 6, lane = t & 63;
  f32x4 acc[4] = {};

#define STAGE_SIM(b, k0) do { \
    _Pragma("unroll") \
    for (int q = 0; q < 2; ++q) { \
      int f_ = t * 8 + q * 2048; \
      int row_ = f_ >> 6; \
      int col_ = (f_ & 63) ^ ((row_ & 7) << 3); \
      gload16(Xb + (size_t)row_ * NFEAT + (k0) + col_, (void*)(Xs[b] + q * 2048 + w * 512)); \
    } } while (0)

  STAGE_SIM(0, 0);
  __syncthreads();
  for (int it = 0; it < 16; ++it) {
    int cur = it & 1;
    if (it < 15) STAGE_SIM(cur ^ 1, (it + 1) * 64);
    const char* base = (const char*)Xs[cur];
#pragma unroll
    for (int ks = 0; ks < 2; ++ks) {
      int koff = ks * 32 + (lane >> 4) * 8;
      int arow = w * 16 + (lane & 15);
      bf16x8 af = *(const bf16x8*)(base + (((arow << 7) + (koff << 1)) ^ ((arow & 7) << 4)));
#pragma unroll
      for (int j = 0; j < 4; ++j) {
        int brow = j * 16 + (lane & 15);
        bf16x8 bf = *(const bf16x8*)(base + (((brow << 7) + (koff << 1)) ^ ((brow & 7) << 4)));
        acc[j] = __builtin_amdgcn_mfma_f32_16x16x32_bf16(af, bf, acc[j], 0, 0, 0);
      }
    }
    __syncthreads();
  }
#undef STAGE_SIM

#pragma unroll
  for (int j = 0; j < 4; ++j)
#pragma unroll
    for (int e = 0; e < 4; ++e) {
      int r = w * 16 + (lane >> 4) * 4 + e;
      int c = j * 16 + (lane & 15);
      float cc = acc[j][e] * 0.99999f;
      cc = fminf(fmaxf(cc, -0.99999f), 0.99999f);
      simS[r][c] = acosf(cc);
    }
  __syncthreads();
  if (t < 64) {
    float s = 0.f;
#pragma unroll 8
    for (int c = 0; c < 64; ++c) s += simS[t][c];
    float di = rsqrtf(s + 1.99998f);
    simS[t][64] = di;
    dinv[blk * 64 + t] = di;
  }
  __syncthreads();
  ushort_t* Sb = Sbf + (size_t)blk * 4096;
#pragma unroll
  for (int q = 0; q < 2; ++q) {
    int idx = t * 8 + q * 2048;
    int i = idx >> 6, j0 = idx & 63;
    float di = simS[i][64];
    u16x8 o;
#pragma unroll
    for (int e = 0; e < 8; ++e)
      o[e] = f2bf(simS[i][j0 + e] * di * simS[j0 + e][64]);
    *reinterpret_cast<u16x8*>(Sb + idx) = o;
  }
}

// ---------- transpose+convert weights: src f32 [K][512] -> dst bf16 [512][K] ----------
__global__ void k_cvt_w(const float* __restrict__ s0, const float* __restrict__ s1,
                        const float* __restrict__ s2, ushort_t* __restrict__ dst,
                        int K, int mode) {
  __shared__ float tile[32][33];
  int z = blockIdx.z;
  const float* src = (mode == 1) ? (s0 + (size_t)z * K * NHID)
                                 : (z == 0 ? s0 : (z == 1 ? s1 : s2));
  ushort_t* d = dst + (size_t)z * NHID * K;
  int n0 = blockIdx.x * 32, k0 = blockIdx.y * 32;
  int tx = threadIdx.x & 31, ty = threadIdx.x >> 5;
#pragma unroll
  for (int q = 0; q < 4; ++q)
    tile[ty + q * 8][tx] = src[(size_t)(k0 + ty + q * 8) * NHID + n0 + tx];
  __syncthreads();
#pragma unroll
  for (int q = 0; q < 4; ++q)
    d[(size_t)(n0 + ty + q * 8) * K + k0 + tx] = f2bf(tile[tx][ty + q * 8]);
}

// ---------- FC bf16 MFMA GEMM, tile 128x64, BK=64, 2-phase (round-4 form) ----------
__global__ __launch_bounds__(256) void k_fc(
    const ushort_t* __restrict__ A, const ushort_t* __restrict__ B,
    const float* __restrict__ ba, const float* __restrict__ bv, const float* __restrict__ bl,
    ushort_t* __restrict__ C, ushort_t* __restrict__ C2) {
  __shared__ short As[2][128 * 64];
  __shared__ short Bs[2][64 * 64];
  const int K = NFEAT;
  int t = threadIdx.x;
  int w = t >> 6, lane = t & 63;
  int bm = blockIdx.x * 128, bn = blockIdx.y * 64;
  int band = bm / NROW;
  B += (size_t)band * NHID * K;
  const float* bias = (band == 0 ? ba : (band == 1 ? bv : bl));
  const ushort_t* Ab = A + (size_t)bm * K;
  const ushort_t* Bb = B + (size_t)bn * K;
  int wr = (w >> 1) * 64, wc = (w & 1) * 32;
  f32x4 acc[4][2] = {};

#define STAGE_G(b, k0) do { \
    _Pragma("unroll") \
    for (int q = 0; q < 4; ++q) { \
      int f_ = t * 8 + q * 2048; int row_ = f_ >> 6; \
      int col_ = (f_ & 63) ^ ((row_ & 7) << 3); \
      gload16(Ab + (size_t)row_ * K + (k0) + col_, (void*)(As[b] + q * 2048 + w * 512)); } \
    _Pragma("unroll") \
    for (int q = 0; q < 2; ++q) { \
      int f_ = t * 8 + q * 2048; int row_ = f_ >> 6; \
      int col_ = (f_ & 63) ^ ((row_ & 7) << 3); \
      gload16(Bb + (size_t)row_ * K + (k0) + col_, (void*)(Bs[b] + q * 2048 + w * 512)); } \
  } while (0)

  STAGE_G(0, 0);
  __syncthreads();
  const int T = K >> 6;
  for (int s = 0; s < T; ++s) {
    int cur = s & 1;
    if (s + 1 < T) STAGE_G(cur ^ 1, (s + 1) * 64);
    const char* ab = (const char*)As[cur];
    const char* bb = (const char*)Bs[cur];
#pragma unroll
    for (int ks = 0; ks < 2; ++ks) {
      bf16x8 af[4], bfr[2];
#pragma unroll
      for (int i = 0; i < 4; ++i) {
        int arow = wr + i * 16 + (lane & 15);
        int abo = (arow << 7) + ((ks * 32 + (lane >> 4) * 8) << 1);
        af[i] = *reinterpret_cast<const bf16x8*>(ab + (abo ^ ((arow & 7) << 4)));
      }
#pragma unroll
      for (int j = 0; j < 2; ++j) {
        int brow = wc + j * 16 + (lane & 15);
        int bbo = (brow << 7) + ((ks * 32 + (lane >> 4) * 8) << 1);
        bfr[j] = *reinterpret_cast<const bf16x8*>(bb + (bbo ^ ((brow & 7) << 4)));
      }
#pragma unroll
      for (int i = 0; i < 4; ++i)
#pragma unroll
        for (int j = 0; j < 2; ++j)
          acc[i][j] = __builtin_amdgcn_mfma_f32_16x16x32_bf16(af[i], bfr[j], acc[i][j], 0, 0, 0);
    }
    __syncthreads();
  }
#undef STAGE_G

#pragma unroll
  for (int i = 0; i < 4; ++i) {
#pragma unroll
    for (int jf = 0; jf < 2; ++jf) {
      int r0 = bm + wr + i * 16 + (lane >> 4) * 4;
      int c  = bn + wc + jf * 16 + (lane & 15);
#pragma unroll
      for (int j = 0; j < 4; ++j) {
        int r = r0 + j;
        float val = fmaxf(acc[i][jf][j] + bias[c], 0.f);
        unsigned short o = f2bf(val);
        C[(size_t)r * NHID + c] = o;
        C2[(size_t)r * NHID + c] = o;
      }
    }
  }
}

// ---------- FUSED layer: sup = 0.9*(S@h + cross) + 0.1*h0 (in LDS), then
//            h_out = relu(theta*(sup@Wc) + (1-theta)*sup).  One dispatch/layer.
// block = (d, m, col-half): rows g0..g0+63, output cols bn..bn+255.
__global__ __launch_bounds__(256) void k_layer(
    const ushort_t* __restrict__ Sbf, const ushort_t* __restrict__ Wct_i,
    const ushort_t* __restrict__ hin, const ushort_t* __restrict__ h0,
    const float* __restrict__ dinv, ushort_t* __restrict__ hout, float theta) {
  __shared__ char lds[160768];
  ushort_t* supL   = (ushort_t*)lds;                     // [64][512] bf16, swizzled (64KB)
  short* Ss        = (short*)(lds + 65536);              // 8KB  (phase 1)
  short (*Ht)[68]  = (short (*)[68])(lds + 73728);       // [512][68] transposed h_own (68KB)
  float (*supS)[68]= (float (*)[68])(lds + 143360);      // [64][68] f32 scratch (17KB)
  short* Bs        = (short*)(lds + 65536);              // phase 2: [2][16384] Wc dbuf (64KB)

  int lin = blockIdx.x;
  int d = lin / 6, rem = lin % 6;
  int m = rem >> 1, half = rem & 1;
  int bn = half * 256;
  int t = threadIdx.x, w = t >> 6, lane = t & 63;
  int m1 = (m == 2) ? 0 : m + 1, m2 = (m == 0) ? 2 : m - 1;
  int g0 = m * NROW + d * 64, g1 = m1 * NROW + d * 64, g2 = m2 * NROW + d * 64;

  // ---- phase 1 staging: S block (swizzled) + full transposed h_own ----
  const ushort_t* Sb = Sbf + (size_t)(m * NDIA + d) * 4096;
#pragma unroll
  for (int q = 0; q < 2; ++q) {
    int f = t * 8 + q * 2048;
    int row = f >> 6, col = (f & 63) ^ ((row & 7) << 3);
    gload16(Sb + row * 64 + col, (void*)(Ss + q * 2048 + w * 512));
  }
#pragma unroll
  for (int q = 0; q < 16; ++q) {
    int j = w + q * 4;                       // wave-uniform row
    int n0 = (t & 63) * 8;                   // col group: wave reads one full 1KB row
    u16x8 hv = *reinterpret_cast<const u16x8*>(hin + (size_t)(g0 + j) * NHID + n0);
    int js = j ^ ((t & 7) << 3);             // key = (n0>>3)&7 = t&7
#pragma unroll
    for (int e = 0; e < 8; ++e) Ht[n0 + e][js] = hv[e];
  }

  // per-thread repack constants
  int rr = t >> 2, c16 = (t & 3) * 16;
  int u = d * 64 + rr;
  float dm = dinv[m * NROW + u];
  float c1 = 0.99999f * dm * dinv[m1 * NROW + u];
  float c2 = 0.99999f * dm * dinv[m2 * NROW + u];

  u16x8 pf[2][6];
#define PF(slot, kc) do { \
    const ushort_t* q1 = hin + (size_t)(g1 + rr) * NHID + (kc) * 64 + c16; \
    const ushort_t* q2 = hin + (size_t)(g2 + rr) * NHID + (kc) * 64 + c16; \
    const ushort_t* qz = h0 + (size_t)(g0 + rr) * NHID + (kc) * 64 + c16;  \
    pf[slot][0] = *(const u16x8*)q1; pf[slot][1] = *(const u16x8*)(q1 + 8); \
    pf[slot][2] = *(const u16x8*)q2; pf[slot][3] = *(const u16x8*)(q2 + 8); \
    pf[slot][4] = *(const u16x8*)qz; pf[slot][5] = *(const u16x8*)(qz + 8); \
  } while (0)
  PF(0, 0);
  __syncthreads();

  // ---- S@h MFMA: all 8 col-chunks back-to-back ----
  f32x4 accc[8][4] = {};
  int arow = w * 16 + (lane & 15);
#pragma unroll
  for (int ks = 0; ks < 2; ++ks) {
    int koff = ks * 32 + (lane >> 4) * 8;
    bf16x8 af = *(const bf16x8*)((const char*)Ss +
                  (((arow << 7) + (koff << 1)) ^ ((arow & 7) << 4)));
#pragma unroll
    for (int kc = 0; kc < 8; ++kc)
#pragma unroll
      for (int j = 0; j < 4; ++j) {
        int n = kc * 64 + j * 16 + (lane & 15);
        int koff_s = koff ^ (((n >> 3) & 7) << 3);
        bf16x8 bf = *(const bf16x8*)(&Ht[n][koff_s]);
        accc[kc][j] = __builtin_amdgcn_mfma_f32_16x16x32_bf16(af, bf, accc[kc][j], 0, 0, 0);
      }
  }

  // ---- per-chunk: supS roundtrip + cross/h0 fuse -> supL (bf16, swizzled) ----
#pragma unroll
  for (int kc = 0; kc < 8; ++kc) {
    if (kc < 7) PF((kc + 1) & 1, kc + 1);     // prefetch next chunk's operands
#pragma unroll
    for (int j = 0; j < 4; ++j)
#pragma unroll
      for (int e = 0; e < 4; ++e)
        supS[w * 16 + (lane >> 4) * 4 + e][j * 16 + (lane & 15)] = accc[kc][j][e];
    __syncthreads();
    const u16x8* P = pf[kc & 1];
#pragma unroll
    for (int hh = 0; hh < 2; ++hh) {
      u16x8 o;
#pragma unroll
      for (int e = 0; e < 8; ++e) {
        float val = 0.9f * (supS[rr][c16 + hh * 8 + e]
                    + c1 * bf2f(P[hh][e]) + c2 * bf2f(P[2 + hh][e]))
                  + 0.1f * bf2f(P[4 + hh][e]);
        o[e] = f2bf(val);
      }
      int byte = rr * 1024 + (kc * 64 + c16 + hh * 8) * 2;
      *reinterpret_cast<u16x8*>((char*)supL + (byte ^ ((rr & 7) << 4))) = o;
    }
    __syncthreads();
  }
#undef PF

  // ---- phase 2: h_out[64][256] = relu(theta*(supL @ Wc[:,bn:bn+256]) + (1-theta)*supL) ----
  const ushort_t* Wb = Wct_i + (size_t)bn * NHID;
#define STAGE_W(b, k0) do { \
    _Pragma("unroll") \
    for (int q = 0; q < 8; ++q) { \
      int f = t * 8 + q * 2048; \
      int n_ = f >> 6, col = (f & 63) ^ ((n_ & 7) << 3); \
      gload16(Wb + (size_t)n_ * NHID + (k0) + col, (void*)(Bs + (b) * 16384 + q * 2048 + w * 512)); \
    } } while (0)

  f32x4 acc[4][4] = {};
  STAGE_W(0, 0);
  __syncthreads();
#pragma unroll 1
  for (int s = 0; s < 8; ++s) {
    int cur = s & 1;
    if (s < 7) STAGE_W(cur ^ 1, (s + 1) * 64);
    const char* bb = (const char*)(Bs + cur * 16384);
#pragma unroll
    for (int ks = 0; ks < 2; ++ks) {
      int koff = ks * 32 + (lane >> 4) * 8;
      bf16x8 af[4], bfr[4];
#pragma unroll
      for (int i = 0; i < 4; ++i) {
        int ar = i * 16 + (lane & 15);
        af[i] = *(const bf16x8*)((const char*)supL +
                 ((ar * 1024 + (s * 64 + koff) * 2) ^ ((ar & 7) << 4)));
      }
#pragma unroll
      for (int j = 0; j < 4; ++j) {
        int nl = w * 64 + j * 16 + (lane & 15);
        bfr[j] = *(const bf16x8*)(bb + (((nl << 7) + (koff << 1)) ^ ((nl & 7) << 4)));
      }
#pragma unroll
      for (int i = 0; i < 4; ++i)
#pragma unroll
        for (int j = 0; j < 4; ++j)
          acc[i][j] = __builtin_amdgcn_mfma_f32_16x16x32_bf16(af[i], bfr[j], acc[i][j], 0, 0, 0);
    }
    __syncthreads();
  }
#undef STAGE_W

  float omt = 1.f - theta;
#pragma unroll
  for (int i = 0; i < 4; ++i) {
#pragma unroll
    for (int j = 0; j < 4; ++j) {
      int cl = w * 64 + j * 16 + (lane & 15);
      int cg = bn + cl;
#pragma unroll
      for (int e = 0; e < 4; ++e) {
        int r = i * 16 + (lane >> 4) * 4 + e;
        float supv = bf2f(*(const ushort_t*)((const char*)supL +
                       ((r * 1024 + cg * 2) ^ ((r & 7) << 4))));
        float val = fmaxf(theta * acc[i][j][e] + omt * supv, 0.f);
        hout[(size_t)(g0 + r) * NHID + cg] = f2bf(val);
      }
    }
  }
}

// ---------- assemble output: [ l(f32) | h(bf16->f32) ] ----------
__global__ void k_out(const float* __restrict__ l, const ushort_t* __restrict__ h,
                      float* __restrict__ out) {
  int idx = blockIdx.x * blockDim.x + threadIdx.x;
  int i = idx / 640;
  int c4 = (idx % 640) * 4;
  float4 val;
  if (c4 < 1024) {
    val = *reinterpret_cast<const float4*>(l + (size_t)i * NFEAT + c4);
  } else {
    int cc = c4 - 1024;
    int m = cc >> 9, c = cc & 511;
    u16x4 hv = *reinterpret_cast<const u16x4*>(h + ((size_t)m * NROW + i) * NHID + c);
    val.x = bf2f(hv[0]); val.y = bf2f(hv[1]); val.z = bf2f(hv[2]); val.w = bf2f(hv[3]);
  }
  *reinterpret_cast<float4*>(out + (size_t)i * 2560 + c4) = val;
}

extern "C" void kernel_launch(void* const* d_in, const int* in_sizes, int n_in,
                              void* d_out, int out_size, void* d_ws, size_t ws_size,
                              hipStream_t stream) {
  const float* a  = (const float*)d_in[0];
  const float* v  = (const float*)d_in[1];
  const float* l  = (const float*)d_in[2];
  const float* W0 = (const float*)d_in[3];
  const float* b0 = (const float*)d_in[4];
  const float* W1 = (const float*)d_in[5];
  const float* b1 = (const float*)d_in[6];
  const float* W2 = (const float*)d_in[7];
  const float* b2 = (const float*)d_in[8];
  const float* Wc = (const float*)d_in[9];
  float* out = (float*)d_out;

  const size_t SZ = (size_t)NROW3 * NHID;             // 4,718,592 elements
  const size_t XSZ = (size_t)3 * NROW * NFEAT;        // 9,437,184 elements
  char* ws = (char*)d_ws;
  ushort_t* Abuf = (ushort_t*)ws;  ws += XSZ * 2;     // raw bf16 inputs (live through FC)
  ushort_t* Xn   = (ushort_t*)ws;  ws += XSZ * 2;     // normalized; dead after k_simm
  ushort_t* h0   = (ushort_t*)ws;  ws += SZ * 2;
  ushort_t* Wtfc = (ushort_t*)ws;  ws += (size_t)3 * NHID * NFEAT * 2;
  ushort_t* Wct  = (ushort_t*)ws;  ws += (size_t)NLAYERS * NHID * NHID * 2;
  ushort_t* Sbf  = (ushort_t*)ws;  ws += (size_t)144 * 4096 * 2;
  float* dinv    = (float*)ws;
  ushort_t* hA = Xn;             // alias: Xn dead once k_simm completes
  ushort_t* hB = Xn + SZ;        // ping-pong partner (2*SZ == XSZ)

  k_prep<<<NROW3 / 4, 256, 0, stream>>>(a, v, l, Abuf, Xn);
  k_cvt_w<<<dim3(NHID / 32, NFEAT / 32, 3), 256, 0, stream>>>(W0, W2, W1, Wtfc, NFEAT, 0);
  k_cvt_w<<<dim3(NHID / 32, NHID / 32, NLAYERS), 256, 0, stream>>>(Wc, nullptr, nullptr, Wct, NHID, 1);
  k_simm<<<3 * NDIA, 256, 0, stream>>>(Xn, Sbf, dinv);

  // fused FC -> writes BOTH h0 and hA
  k_fc<<<dim3(NROW3 / 128, NHID / 64), 256, 0, stream>>>(Abuf, Wtfc, b0, b2, b1, h0, hA);

  ushort_t* cur = hA;
  ushort_t* nxt = hB;
  for (int i = 0; i < NLAYERS; ++i) {
    float theta = (float)std::log(0.5 / (i + 1) + 1.0);
    k_layer<<<288, 256, 0, stream>>>(Sbf, Wct + (size_t)i * NHID * NHID,
                                     cur, h0, dinv, nxt, theta);
    ushort_t* tmp = cur; cur = nxt; nxt = tmp;
  }
  // 8 layers (even) -> final h is back in hA == cur

  k_out<<<(NROW * 2560 / 4) / 256, 256, 0, stream>>>(l, cur, out);
}

// Round 8
// 239.316 us; speedup vs baseline: 1.8115x; 1.8115x over previous
//
#include <hip/hip_runtime.h>
#include <hip/hip_bf16.h>
#include <cmath>

#define NFEAT 1024
#define NHID  512
#define NLAYERS 8
#define NDIA 48
#define DIAL 64
#define NROW (NDIA*DIAL)   // 3072
#define NROW3 (3*NROW)     // 9216

typedef short bf16x8 __attribute__((ext_vector_type(8)));
typedef float f32x4  __attribute__((ext_vector_type(4)));
typedef unsigned short u16x8 __attribute__((ext_vector_type(8)));
typedef unsigned short u16x4 __attribute__((ext_vector_type(4)));
typedef unsigned short ushort_t;

struct Thetas { float th[NLAYERS]; };

__device__ __forceinline__ unsigned short f2bf(float x) {
  __hip_bfloat16 h = __float2bfloat16(x);
  return __builtin_bit_cast(unsigned short, h);
}
__device__ __forceinline__ float bf2f(unsigned short u) {
  __hip_bfloat16 h = __builtin_bit_cast(__hip_bfloat16, u);
  return __bfloat162float(h);
}

__device__ __forceinline__ void gload16(const void* g, void* l) {
  __builtin_amdgcn_global_load_lds(
      (const __attribute__((address_space(1))) void*)g,
      (__attribute__((address_space(3))) void*)l, 16, 0, 0);
}

// ---------- manual grid barrier (monotonic counter, device scope) ----------
__device__ __forceinline__ void gbar(unsigned* bar, unsigned target) {
  __threadfence();               // all threads: release prior global writes
  __syncthreads();
  if (threadIdx.x == 0) {
    __hip_atomic_fetch_add(bar, 1u, __ATOMIC_RELEASE, __HIP_MEMORY_SCOPE_AGENT);
    int cap = 50000000;          // bounded spin: never hangs
    while (__hip_atomic_load(bar, __ATOMIC_ACQUIRE, __HIP_MEMORY_SCOPE_AGENT) < target) {
      __builtin_amdgcn_s_sleep(2);
      if (--cap == 0) break;
    }
  }
  __syncthreads();
}

// ---------- fused: row-norm + bf16 convert (raw and normalized) ----------
__global__ __launch_bounds__(256) void k_prep(const float* __restrict__ a, const float* __restrict__ v,
                      const float* __restrict__ l, ushort_t* __restrict__ Abuf,
                      ushort_t* __restrict__ Xn) {
  int gid = blockIdx.x * 256 + threadIdx.x;
  int row = gid >> 6, lane = gid & 63;
  int m = row / NROW, r = row % NROW;
  const float* src = (m == 0 ? a : (m == 1 ? v : l)) + (size_t)r * NFEAT;
  float4 x[4];
  float s = 0.f;
#pragma unroll
  for (int q = 0; q < 4; ++q) {
    x[q] = *reinterpret_cast<const float4*>(src + lane * 4 + q * 256);
    s += x[q].x*x[q].x + x[q].y*x[q].y + x[q].z*x[q].z + x[q].w*x[q].w;
  }
#pragma unroll
  for (int off = 32; off; off >>= 1) s += __shfl_xor(s, off);
  float inv = rsqrtf(s);
  ushort_t* da = Abuf + (size_t)row * NFEAT;
  ushort_t* dn = Xn + (size_t)row * NFEAT;
#pragma unroll
  for (int q = 0; q < 4; ++q) {
    u16x4 oa, on;
    oa[0] = f2bf(x[q].x); oa[1] = f2bf(x[q].y); oa[2] = f2bf(x[q].z); oa[3] = f2bf(x[q].w);
    on[0] = f2bf(x[q].x * inv); on[1] = f2bf(x[q].y * inv);
    on[2] = f2bf(x[q].z * inv); on[3] = f2bf(x[q].w * inv);
    *reinterpret_cast<u16x4*>(da + lane * 4 + q * 256) = oa;
    *reinterpret_cast<u16x4*>(dn + lane * 4 + q * 256) = on;
  }
}

// ---------- MFMA Gram -> acos -> fused degree+normalize -> bf16 S + dinv ----------
__global__ __launch_bounds__(256) void k_simm(const ushort_t* __restrict__ Xn,
                      ushort_t* __restrict__ Sbf, float* __restrict__ dinv) {
  __shared__ short Xs[2][4096];
  __shared__ float simS[64][73];
  int blk = blockIdx.x;
  const ushort_t* Xb = Xn + (size_t)blk * 64 * NFEAT;
  int t = threadIdx.x, w = t >> 6, lane = t & 63;
  f32x4 acc[4] = {};

#define STAGE_SIM(b, k0) do { \
    _Pragma("unroll") \
    for (int q = 0; q < 2; ++q) { \
      int f_ = t * 8 + q * 2048; \
      int row_ = f_ >> 6; \
      int col_ = (f_ & 63) ^ ((row_ & 7) << 3); \
      gload16(Xb + (size_t)row_ * NFEAT + (k0) + col_, (void*)(Xs[b] + q * 2048 + w * 512)); \
    } } while (0)

  STAGE_SIM(0, 0);
  __syncthreads();
  for (int it = 0; it < 16; ++it) {
    int cur = it & 1;
    if (it < 15) STAGE_SIM(cur ^ 1, (it + 1) * 64);
    const char* base = (const char*)Xs[cur];
#pragma unroll
    for (int ks = 0; ks < 2; ++ks) {
      int koff = ks * 32 + (lane >> 4) * 8;
      int arow = w * 16 + (lane & 15);
      bf16x8 af = *(const bf16x8*)(base + (((arow << 7) + (koff << 1)) ^ ((arow & 7) << 4)));
#pragma unroll
      for (int j = 0; j < 4; ++j) {
        int brow = j * 16 + (lane & 15);
        bf16x8 bf = *(const bf16x8*)(base + (((brow << 7) + (koff << 1)) ^ ((brow & 7) << 4)));
        acc[j] = __builtin_amdgcn_mfma_f32_16x16x32_bf16(af, bf, acc[j], 0, 0, 0);
      }
    }
    __syncthreads();
  }
#undef STAGE_SIM

#pragma unroll
  for (int j = 0; j < 4; ++j)
#pragma unroll
    for (int e = 0; e < 4; ++e) {
      int r = w * 16 + (lane >> 4) * 4 + e;
      int c = j * 16 + (lane & 15);
      float cc = acc[j][e] * 0.99999f;
      cc = fminf(fmaxf(cc, -0.99999f), 0.99999f);
      simS[r][c] = acosf(cc);
    }
  __syncthreads();
  if (t < 64) {
    float s = 0.f;
#pragma unroll 8
    for (int c = 0; c < 64; ++c) s += simS[t][c];
    float di = rsqrtf(s + 1.99998f);
    simS[t][64] = di;
    dinv[blk * 64 + t] = di;
  }
  __syncthreads();
  ushort_t* Sb = Sbf + (size_t)blk * 4096;
#pragma unroll
  for (int q = 0; q < 2; ++q) {
    int idx = t * 8 + q * 2048;
    int i = idx >> 6, j0 = idx & 63;
    float di = simS[i][64];
    u16x8 o;
#pragma unroll
    for (int e = 0; e < 8; ++e)
      o[e] = f2bf(simS[i][j0 + e] * di * simS[j0 + e][64]);
    *reinterpret_cast<u16x8*>(Sb + idx) = o;
  }
}

// ---------- transpose+convert weights: src f32 [K][512] -> dst bf16 [512][K] ----------
__global__ void k_cvt_w(const float* __restrict__ s0, const float* __restrict__ s1,
                        const float* __restrict__ s2, ushort_t* __restrict__ dst,
                        int K, int mode) {
  __shared__ float tile[32][33];
  int z = blockIdx.z;
  const float* src = (mode == 1) ? (s0 + (size_t)z * K * NHID)
                                 : (z == 0 ? s0 : (z == 1 ? s1 : s2));
  ushort_t* d = dst + (size_t)z * NHID * K;
  int n0 = blockIdx.x * 32, k0 = blockIdx.y * 32;
  int tx = threadIdx.x & 31, ty = threadIdx.x >> 5;
#pragma unroll
  for (int q = 0; q < 4; ++q)
    tile[ty + q * 8][tx] = src[(size_t)(k0 + ty + q * 8) * NHID + n0 + tx];
  __syncthreads();
#pragma unroll
  for (int q = 0; q < 4; ++q)
    d[(size_t)(n0 + ty + q * 8) * K + k0 + tx] = f2bf(tile[tx][ty + q * 8]);
}

// ---------- FC bf16 MFMA GEMM, tile 128x64, BK=64, 2-phase ----------
__global__ __launch_bounds__(256) void k_fc(
    const ushort_t* __restrict__ A, const ushort_t* __restrict__ B,
    const float* __restrict__ ba, const float* __restrict__ bv, const float* __restrict__ bl,
    ushort_t* __restrict__ C, ushort_t* __restrict__ C2) {
  __shared__ short As[2][128 * 64];
  __shared__ short Bs[2][64 * 64];
  const int K = NFEAT;
  int t = threadIdx.x;
  int w = t >> 6, lane = t & 63;
  int bm = blockIdx.x * 128, bn = blockIdx.y * 64;
  int band = bm / NROW;
  B += (size_t)band * NHID * K;
  const float* bias = (band == 0 ? ba : (band == 1 ? bv : bl));
  const ushort_t* Ab = A + (size_t)bm * K;
  const ushort_t* Bb = B + (size_t)bn * K;
  int wr = (w >> 1) * 64, wc = (w & 1) * 32;
  f32x4 acc[4][2] = {};

#define STAGE_G(b, k0) do { \
    _Pragma("unroll") \
    for (int q = 0; q < 4; ++q) { \
      int f_ = t * 8 + q * 2048; int row_ = f_ >> 6; \
      int col_ = (f_ & 63) ^ ((row_ & 7) << 3); \
      gload16(Ab + (size_t)row_ * K + (k0) + col_, (void*)(As[b] + q * 2048 + w * 512)); } \
    _Pragma("unroll") \
    for (int q = 0; q < 2; ++q) { \
      int f_ = t * 8 + q * 2048; int row_ = f_ >> 6; \
      int col_ = (f_ & 63) ^ ((row_ & 7) << 3); \
      gload16(Bb + (size_t)row_ * K + (k0) + col_, (void*)(Bs[b] + q * 2048 + w * 512)); } \
  } while (0)

  STAGE_G(0, 0);
  __syncthreads();
  const int T = K >> 6;
  for (int s = 0; s < T; ++s) {
    int cur = s & 1;
    if (s + 1 < T) STAGE_G(cur ^ 1, (s + 1) * 64);
    const char* ab = (const char*)As[cur];
    const char* bb = (const char*)Bs[cur];
#pragma unroll
    for (int ks = 0; ks < 2; ++ks) {
      bf16x8 af[4], bfr[2];
#pragma unroll
      for (int i = 0; i < 4; ++i) {
        int arow = wr + i * 16 + (lane & 15);
        int abo = (arow << 7) + ((ks * 32 + (lane >> 4) * 8) << 1);
        af[i] = *reinterpret_cast<const bf16x8*>(ab + (abo ^ ((arow & 7) << 4)));
      }
#pragma unroll
      for (int j = 0; j < 2; ++j) {
        int brow = wc + j * 16 + (lane & 15);
        int bbo = (brow << 7) + ((ks * 32 + (lane >> 4) * 8) << 1);
        bfr[j] = *reinterpret_cast<const bf16x8*>(bb + (bbo ^ ((brow & 7) << 4)));
      }
#pragma unroll
      for (int i = 0; i < 4; ++i)
#pragma unroll
        for (int j = 0; j < 2; ++j)
          acc[i][j] = __builtin_amdgcn_mfma_f32_16x16x32_bf16(af[i], bfr[j], acc[i][j], 0, 0, 0);
    }
    __syncthreads();
  }
#undef STAGE_G

#pragma unroll
  for (int i = 0; i < 4; ++i) {
#pragma unroll
    for (int jf = 0; jf < 2; ++jf) {
      int r0 = bm + wr + i * 16 + (lane >> 4) * 4;
      int c  = bn + wc + jf * 16 + (lane & 15);
#pragma unroll
      for (int j = 0; j < 4; ++j) {
        int r = r0 + j;
        float val = fmaxf(acc[i][jf][j] + bias[c], 0.f);
        unsigned short o = f2bf(val);
        C[(size_t)r * NHID + c] = o;
        C2[(size_t)r * NHID + c] = o;
      }
    }
  }
}

// ================= phase A (round-4 k_adj, supS overlays Ss) =================
// block b: d = b>>3, col chunk c0 = (b&7)*64. LDS use: [0,52224)
__device__ __forceinline__ void phaseA_dev(int b, const ushort_t* __restrict__ Sbf,
    const ushort_t* __restrict__ h, const ushort_t* __restrict__ h0,
    const float* __restrict__ dinv, ushort_t* __restrict__ sup, char* lds) {
  short* Ss = (short*)lds;                           // 3*4096 shorts [0,24576)
  short (*Ht)[72] = (short (*)[72])(lds + 24576);    // [192][72]     [24576,52224)
  float (*supS)[69] = (float (*)[69])lds;            // overlay on Ss after MFMA
  int t = threadIdx.x, w = t >> 6, lane = t & 63;
  int d = b >> 3, c0 = (b & 7) << 6;
#pragma unroll
  for (int q = 0; q < 6; ++q) {
    int f = t * 8 + q * 2048;
    int mod = f >> 12, rem = f & 4095;
    int row = rem >> 6;
    int col = (rem & 63) ^ ((row & 7) << 3);
    gload16(Sbf + ((size_t)(mod * NDIA + d)) * 4096 + row * 64 + col,
            (void*)(Ss + q * 2048 + w * 512));
  }
#pragma unroll
  for (int q = 0; q < 6; ++q) {
    int idx = t + q * 256;
    int mod = idx >> 9, rem = idx & 511;
    int j = rem >> 3, n0 = (rem & 7) * 8;
    int key = rem & 7;
    u16x8 hv = *reinterpret_cast<const u16x8*>(
        h + ((size_t)(mod * NROW + d * 64 + j)) * NHID + c0 + n0);
    int js = j ^ (key << 3);
#pragma unroll
    for (int e = 0; e < 8; ++e) Ht[mod * 64 + n0 + e][js] = hv[e];
  }
  __syncthreads();
  f32x4 acc[3][4] = {};
#pragma unroll
  for (int m = 0; m < 3; ++m)
#pragma unroll
    for (int ks = 0; ks < 2; ++ks) {
      int koff = ks * 32 + (lane >> 4) * 8;
      int arow = w * 16 + (lane & 15);
      bf16x8 af = *(const bf16x8*)((const char*)Ss + m * 8192 +
                    (((arow << 7) + (koff << 1)) ^ ((arow & 7) << 4)));
#pragma unroll
      for (int j = 0; j < 4; ++j) {
        int n = j * 16 + (lane & 15);
        int koff_s = koff ^ (((n >> 3) & 7) << 3);
        bf16x8 bf = *(const bf16x8*)(&Ht[m * 64 + n][koff_s]);
        acc[m][j] = __builtin_amdgcn_mfma_f32_16x16x32_bf16(af, bf, acc[m][j], 0, 0, 0);
      }
    }
  __syncthreads();          // Ss reads complete before supS overlay writes
  int r = t >> 2, cc0 = (t & 3) * 16;
  int u = d * 64 + r;
  float dv[3] = {dinv[u], dinv[NROW + u], dinv[2 * NROW + u]};
  for (int m = 0; m < 3; ++m) {
#pragma unroll
    for (int j = 0; j < 4; ++j)
#pragma unroll
      for (int e = 0; e < 4; ++e)
        supS[w * 16 + (lane >> 4) * 4 + e][j * 16 + (lane & 15)] = acc[m][j][e];
    __syncthreads();
    int mm1 = (m + 1) % 3, mm2 = (m + 2) % 3;
    int g = m * NROW + u;
    float c1 = 0.99999f * dv[m] * dv[mm1];
    float c2 = 0.99999f * dv[m] * dv[mm2];
    const ushort_t* p1 = h + ((size_t)(mm1 * NROW + u)) * NHID + c0 + cc0;
    const ushort_t* p2 = h + ((size_t)(mm2 * NROW + u)) * NHID + c0 + cc0;
    const ushort_t* pz = h0 + (size_t)g * NHID + c0 + cc0;
    ushort_t* po = sup + (size_t)g * NHID + c0 + cc0;
#pragma unroll
    for (int half = 0; half < 2; ++half) {
      u16x8 h1 = *reinterpret_cast<const u16x8*>(p1 + half * 8);
      u16x8 h2 = *reinterpret_cast<const u16x8*>(p2 + half * 8);
      u16x8 hz = *reinterpret_cast<const u16x8*>(pz + half * 8);
      u16x8 o;
#pragma unroll
      for (int e = 0; e < 8; ++e) {
        float val = 0.9f * (supS[r][cc0 + half * 8 + e] + c1 * bf2f(h1[e]) + c2 * bf2f(h2[e]))
                  + 0.1f * bf2f(hz[e]);
        o[e] = f2bf(val);
      }
      *reinterpret_cast<u16x8*>(po + half * 8) = o;
    }
    __syncthreads();
  }
}

// ================= phase B: h = relu(theta*(sup@Wc) + (1-theta)*sup) =================
// block b: bm = (b>>2)*96, bn = (b&3)*128. LDS use: [0,57344)
__device__ __forceinline__ void phaseB_dev(int b, const ushort_t* __restrict__ sup,
    const ushort_t* __restrict__ Wl, ushort_t* __restrict__ h, float theta, char* lds) {
  short* As0 = (short*)lds;              // 2 x 96*64 shorts  [0,24576)
  short* Bs0 = (short*)(lds + 24576);    // 2 x 128*64 shorts [24576,57344)
  int t = threadIdx.x, w = t >> 6, lane = t & 63;
  int bm = (b >> 2) * 96, bn = (b & 3) * 128;
  const ushort_t* Ab = sup + (size_t)bm * NHID;
  const ushort_t* Bb = Wl + (size_t)bn * NHID;
  f32x4 acc[6][2] = {};

#define STAGE_B(bb_, k0) do { \
    _Pragma("unroll") \
    for (int q = 0; q < 3; ++q) { \
      int f_ = t * 8 + q * 2048; int row_ = f_ >> 6; \
      int col_ = (f_ & 63) ^ ((row_ & 7) << 3); \
      gload16(Ab + (size_t)row_ * NHID + (k0) + col_, (void*)(As0 + (bb_) * 6144 + q * 2048 + w * 512)); } \
    _Pragma("unroll") \
    for (int q = 0; q < 4; ++q) { \
      int f_ = t * 8 + q * 2048; int row_ = f_ >> 6; \
      int col_ = (f_ & 63) ^ ((row_ & 7) << 3); \
      gload16(Bb + (size_t)row_ * NHID + (k0) + col_, (void*)(Bs0 + (bb_) * 8192 + q * 2048 + w * 512)); } \
  } while (0)

  STAGE_B(0, 0);
  __syncthreads();
  for (int s = 0; s < 8; ++s) {
    int cur = s & 1;
    if (s + 1 < 8) STAGE_B(cur ^ 1, (s + 1) * 64);
    const char* ab = (const char*)(As0 + cur * 6144);
    const char* bb = (const char*)(Bs0 + cur * 8192);
#pragma unroll
    for (int ks = 0; ks < 2; ++ks) {
      int koff = ks * 32 + (lane >> 4) * 8;
      bf16x8 af[6], bfr[2];
#pragma unroll
      for (int i = 0; i < 6; ++i) {
        int arow = i * 16 + (lane & 15);
        af[i] = *reinterpret_cast<const bf16x8*>(ab +
                  (((arow << 7) + (koff << 1)) ^ ((arow & 7) << 4)));
      }
#pragma unroll
      for (int j = 0; j < 2; ++j) {
        int brow = w * 32 + j * 16 + (lane & 15);
        bfr[j] = *reinterpret_cast<const bf16x8*>(bb +
                  (((brow << 7) + (koff << 1)) ^ ((brow & 7) << 4)));
      }
#pragma unroll
      for (int i = 0; i < 6; ++i)
#pragma unroll
        for (int j = 0; j < 2; ++j)
          acc[i][j] = __builtin_amdgcn_mfma_f32_16x16x32_bf16(af[i], bfr[j], acc[i][j], 0, 0, 0);
    }
    __syncthreads();
  }
#undef STAGE_B

  float omt = 1.f - theta;
#pragma unroll
  for (int i = 0; i < 6; ++i) {
#pragma unroll
    for (int j = 0; j < 2; ++j) {
      int c = bn + w * 32 + j * 16 + (lane & 15);
      int r0 = bm + i * 16 + (lane >> 4) * 4;
#pragma unroll
      for (int e = 0; e < 4; ++e) {
        int r = r0 + e;
        float sv = bf2f(sup[(size_t)r * NHID + c]);
        float val = fmaxf(theta * acc[i][j][e] + omt * sv, 0.f);
        h[(size_t)r * NHID + c] = f2bf(val);
      }
    }
  }
}

// ---------- single-dispatch layer loop with manual grid barrier ----------
__global__ __launch_bounds__(256, 2) void k_sync(
    const ushort_t* __restrict__ Sbf, const ushort_t* __restrict__ Wct,
    ushort_t* __restrict__ h, ushort_t* __restrict__ sup,
    const ushort_t* __restrict__ h0, const float* __restrict__ dinv,
    unsigned* bar, Thetas Th) {
  __shared__ char lds[57344];
  int b = blockIdx.x;
  unsigned target = 0;
  for (int L = 0; L < NLAYERS; ++L) {
    phaseA_dev(b, Sbf, h, h0, dinv, sup, lds);
    target += 384; gbar(bar, target);
    phaseB_dev(b, sup, Wct + (size_t)L * NHID * NHID, h, Th.th[L], lds);
    target += 384; gbar(bar, target);
  }
}

// ---------- fallback: same phases as separate dispatches ----------
__global__ __launch_bounds__(256, 2) void k_adj1(
    const ushort_t* __restrict__ Sbf, const ushort_t* __restrict__ h,
    const ushort_t* __restrict__ h0, const float* __restrict__ dinv,
    ushort_t* __restrict__ sup) {
  __shared__ char lds[52224];
  phaseA_dev(blockIdx.x, Sbf, h, h0, dinv, sup, lds);
}
__global__ __launch_bounds__(256, 2) void k_gemm1(
    const ushort_t* __restrict__ sup, const ushort_t* __restrict__ Wl,
    ushort_t* __restrict__ h, float theta) {
  __shared__ char lds[57344];
  phaseB_dev(blockIdx.x, sup, Wl, h, theta, lds);
}

// ---------- assemble output: [ l(f32) | h(bf16->f32) ] ----------
__global__ void k_out(const float* __restrict__ l, const ushort_t* __restrict__ h,
                      float* __restrict__ out) {
  int idx = blockIdx.x * blockDim.x + threadIdx.x;
  int i = idx / 640;
  int c4 = (idx % 640) * 4;
  float4 val;
  if (c4 < 1024) {
    val = *reinterpret_cast<const float4*>(l + (size_t)i * NFEAT + c4);
  } else {
    int cc = c4 - 1024;
    int m = cc >> 9, c = cc & 511;
    u16x4 hv = *reinterpret_cast<const u16x4*>(h + ((size_t)m * NROW + i) * NHID + c);
    val.x = bf2f(hv[0]); val.y = bf2f(hv[1]); val.z = bf2f(hv[2]); val.w = bf2f(hv[3]);
  }
  *reinterpret_cast<float4*>(out + (size_t)i * 2560 + c4) = val;
}

extern "C" void kernel_launch(void* const* d_in, const int* in_sizes, int n_in,
                              void* d_out, int out_size, void* d_ws, size_t ws_size,
                              hipStream_t stream) {
  const float* a  = (const float*)d_in[0];
  const float* v  = (const float*)d_in[1];
  const float* l  = (const float*)d_in[2];
  const float* W0 = (const float*)d_in[3];
  const float* b0 = (const float*)d_in[4];
  const float* W1 = (const float*)d_in[5];
  const float* b1 = (const float*)d_in[6];
  const float* W2 = (const float*)d_in[7];
  const float* b2 = (const float*)d_in[8];
  const float* Wc = (const float*)d_in[9];
  float* out = (float*)d_out;

  const size_t SZ = (size_t)NROW3 * NHID;             // 4,718,592 elements
  const size_t XSZ = (size_t)3 * NROW * NFEAT;        // 9,437,184 elements
  char* ws = (char*)d_ws;
  ushort_t* Abuf = (ushort_t*)ws;  ws += XSZ * 2;     // raw bf16 inputs (live through FC)
  ushort_t* Xn   = (ushort_t*)ws;  ws += XSZ * 2;     // normalized; dead after k_simm
  ushort_t* h0   = (ushort_t*)ws;  ws += SZ * 2;
  ushort_t* Wtfc = (ushort_t*)ws;  ws += (size_t)3 * NHID * NFEAT * 2;
  ushort_t* Wct  = (ushort_t*)ws;  ws += (size_t)NLAYERS * NHID * NHID * 2;
  ushort_t* Sbf  = (ushort_t*)ws;  ws += (size_t)144 * 4096 * 2;
  float* dinv    = (float*)ws;     ws += (size_t)NROW3 * 4;
  unsigned* bar  = (unsigned*)ws;
  ushort_t* h   = Xn;            // alias: Xn dead once k_simm completes
  ushort_t* sup = Xn + SZ;       // both fit in Xn's footprint (2*SZ == XSZ)

  hipMemsetAsync(bar, 0, 256, stream);   // zero the grid-barrier counter each call

  k_prep<<<NROW3 / 4, 256, 0, stream>>>(a, v, l, Abuf, Xn);
  k_cvt_w<<<dim3(NHID / 32, NFEAT / 32, 3), 256, 0, stream>>>(W0, W2, W1, Wtfc, NFEAT, 0);
  k_cvt_w<<<dim3(NHID / 32, NHID / 32, NLAYERS), 256, 0, stream>>>(Wc, nullptr, nullptr, Wct, NHID, 1);
  k_simm<<<3 * NDIA, 256, 0, stream>>>(Xn, Sbf, dinv);

  // fused FC -> writes BOTH h0 and h (no memcpy)
  k_fc<<<dim3(NROW3 / 128, NHID / 64), 256, 0, stream>>>(Abuf, Wtfc, b0, b2, b1, h0, h);

  Thetas Th;
  for (int i = 0; i < NLAYERS; ++i)
    Th.th[i] = (float)std::log(0.5 / (i + 1) + 1.0);

  // co-residency check: 384 blocks must all fit (2 blocks/CU x 256 CUs = 512)
  int maxb = 0;
  hipError_t oerr = hipOccupancyMaxActiveBlocksPerMultiprocessor(
      &maxb, reinterpret_cast<const void*>(k_sync), 256, 0);
  if (oerr == hipSuccess && maxb >= 2) {
    k_sync<<<384, 256, 0, stream>>>(Sbf, Wct, h, sup, h0, dinv, bar, Th);
  } else {
    for (int i = 0; i < NLAYERS; ++i) {
      k_adj1<<<384, 256, 0, stream>>>(Sbf, h, h0, dinv, sup);
      k_gemm1<<<384, 256, 0, stream>>>(sup, Wct + (size_t)i * NHID * NHID, h, Th.th[i]);
    }
  }

  k_out<<<(NROW * 2560 / 4) / 256, 256, 0, stream>>>(l, h, out);
}